// Round 12
// baseline (294.567 us; speedup 1.0000x reference)
//
#include <hip/hip_runtime.h>
#include <cfloat>
#include <math.h>

// Problem constants
#define BQ 8
#define T 2048
#define D 256
#define DAC 36
#define CH 292
#define K 8192
#define NROWS (BQ*T)          // 16384
#define TAU 1e-3f             // single-bf16-pass error bound + np noise
#define FSPLIT 4              // k-splits in fast kernel (2048 codes each)
#define RSPLIT 16             // k-splits in rescue (512 codes each)
#define CAPROWS 768           // zg capacity (private region; overflow -> scattered)

// Output offsets (floats, reference return order)
#define OFF_IDX   (BQ*CH*T)
#define OFF_CODES (OFF_IDX + NROWS)
#define OFF_LOSS  (OFF_CODES + BQ*DAC*T)
#define OFF_ACQ   (OFF_LOSS + 1)

// ---------------- MFMA-path ws layout, bytes ----------------
#define WN_C2    0                            // float[K]            32 KB
#define WN_Z2    32768                        // float[NROWS]        64 KB
#define WN_CNT   98304                        // int (flag count)
#define WN_LIST  98560                        // int[NROWS]          64 KB
#define WN_LOSS  164096                       // double[512]          4 KB
#define WN_WIDX  168192                       // int[NROWS]          64 KB
#define WN_QCNT  233728                       // int[4]
#define WN_NTC   233744                       // int[128] (per-nt arrival)
#define WN_PMX   262144                       // float4[FSPLIT*NROWS] = 1 MB
#define WN_PR    262144                       // float2[RSPLIT*NROWS] = 2 MB (alias, pmx dead)
#define WN_AZ    2359296                      // ushort[16384][256] = 8 MB (hi only)
#define WN_BC    10747904                     // ushort[8192][256]  = 4 MB (hi only)
#define WN_QL    14942208                     // int[4][NROWS] = 256 KB (queues)
#define WN_ZG    15204352                     // float[768][256] = 768 KB (private)
#define WN_NEED  15990784                     // == R0-proven workspace size

// ---------------- old (fallback) ws layout ----------------
#define WS_C2    0
#define WS_Z2    32768
#define WS_PART  131072
#define WS_IDX   655360
#define WS_LOSS  720896
#define MT 32
#define KT 128
#define DC 32
#define NSPLIT 4

typedef float f32x4 __attribute__((ext_vector_type(4)));
typedef __bf16 bf16x8 __attribute__((ext_vector_type(8)));
typedef __attribute__((address_space(1))) const unsigned int gu32;
typedef __attribute__((address_space(3))) unsigned int lu32;

__device__ inline void gl_lds16(const void* gp, void* lp) {
    __builtin_amdgcn_global_load_lds((gu32*)gp, (lu32*)lp, 16, 0, 0);
}

__device__ inline unsigned short f2bf(float x) {   // RNE, finite inputs
    unsigned u = __float_as_uint(x);
    return (unsigned short)((u + 0x7fffu + ((u >> 16) & 1u)) >> 16);
}

__device__ inline void merge3(float& m1, float& m2, int& mi, float o1, float o2, int oi) {
    if (o1 < m1 || (o1 == m1 && oi < mi)) { m2 = fminf(m1, o2); m1 = o1; mi = oi; }
    else                                  { m2 = fminf(m2, o1); }
}

// ---- numpy pairwise-sum emulation (AVX512 W=16, n=256) ----
template <typename F>
__device__ float np_pairwise256_sq(F ld) {
    float S[2];
    #pragma unroll
    for (int h = 0; h < 2; h++) {
        int base = h * 128;
        float v[16];
        #pragma unroll
        for (int l = 0; l < 16; l++) {
            float q[8];
            #pragma unroll
            for (int j = 0; j < 8; j++) { float x = ld(base + j * 16 + l); q[j] = x * x; }
            v[l] = ((q[0] + q[1]) + (q[2] + q[3])) + ((q[4] + q[5]) + (q[6] + q[7]));
        }
        float t1[8], t2[4], t3[2];
        #pragma unroll
        for (int l = 0; l < 8; l++) t1[l] = v[l] + v[l + 8];
        #pragma unroll
        for (int l = 0; l < 4; l++) t2[l] = t1[l] + t1[l + 4];
        t3[0] = t2[0] + t2[2]; t3[1] = t2[1] + t2[3];
        S[h] = t3[0] + t3[1];
    }
    return S[0] + S[1];
}

// fallback-path helpers
__global__ void k_c2pw(const float* __restrict__ cb, float* __restrict__ c2) {
    int k = blockIdx.x * 256 + threadIdx.x;
    const float* row = cb + (size_t)k * D;
    c2[k] = np_pairwise256_sq([&](int d) { return row[d]; });
}

__global__ void k_z2pw(const float* __restrict__ z, float* __restrict__ z2) {
    int n = blockIdx.x * 256 + threadIdx.x;
    int b = n >> 11, t = n & 2047;
    const float* base = z + (size_t)b * CH * T + t;
    z2[n] = np_pairwise256_sq([&](int d) { return base[(size_t)d * T]; });
}

// ------ fused prep: [0,2048) codebook | [2048,2560) z-prep | [2560,3136) ac -
__global__ __launch_bounds__(256) void k_prep(const float* __restrict__ z,
        const float* __restrict__ cb, unsigned short* __restrict__ Az,
        unsigned short* __restrict__ Bc, float* __restrict__ c2,
        float* __restrict__ z2, int* __restrict__ cnt, int* __restrict__ qcnt,
        int* __restrict__ ntc, float* __restrict__ out) {
    __shared__ float zt[32][260];
    const int tid = threadIdx.x;
    if ((int)blockIdx.x < (K / 4)) {
        const int w = tid >> 6, l = tid & 63;
        const int k = blockIdx.x * 4 + w;
        float4 v = *(const float4*)(cb + (size_t)k * D + l * 4);
        *(float4*)&zt[w][l * 4] = v;
        float fa[4] = {v.x, v.y, v.z, v.w};
        unsigned short hh[4];
        #pragma unroll
        for (int e = 0; e < 4; e++) hh[e] = f2bf(fa[e]);
        *(uint2*)(Bc + (size_t)k * 256 + l * 4) = *(uint2*)hh;
        __syncthreads();
        if (tid < 4) {
            int kk = blockIdx.x * 4 + tid;
            c2[kk] = np_pairwise256_sq([&](int d) { return zt[tid][d]; });
        }
        if (blockIdx.x == 0) {
            if (tid == 0) *cnt = 0;
            if (tid < 4) qcnt[tid] = 0;
            if (tid < 128) ntc[tid] = 0;
        }
    } else if ((int)blockIdx.x < (K / 4) + 512) {
        const int bb = blockIdx.x - (K / 4);
        const int b = bb >> 6, t0 = (bb & 63) * 32;
        for (int i = tid; i < 2048; i += 256) {
            int d = i >> 3, tq = (i & 7) * 4;
            float4 v = *(const float4*)(z + (size_t)(b * CH + d) * T + t0 + tq);
            zt[tq + 0][d] = v.x; zt[tq + 1][d] = v.y;
            zt[tq + 2][d] = v.z; zt[tq + 3][d] = v.w;
        }
        __syncthreads();
        const int t = tid >> 3, c8 = tid & 7;
        unsigned short* rowp = Az + (size_t)(b * 2048 + t0 + t) * 256;
        #pragma unroll
        for (int li = 0; li < 4; li++) {
            int u = c8 + 8 * li;                 // 16B chunk index 0..31
            int dbase = u * 8;
            float f[8];
            *(float4*)&f[0] = *(float4*)&zt[t][dbase];
            *(float4*)&f[4] = *(float4*)&zt[t][dbase + 4];
            unsigned short h[8];
            #pragma unroll
            for (int e = 0; e < 8; e++) h[e] = f2bf(f[e]);
            *(uint4*)(rowp + u * 8) = *(uint4*)h;
        }
        if (tid < 32)
            z2[b * 2048 + t0 + tid] = np_pairwise256_sq([&](int d) { return zt[tid][d]; });
    } else {
        // ---- ac path (independent of VQ) ----
        const int ab = blockIdx.x - ((K / 4) + 512);
        int i = (ab * 256 + tid) * 4;            // grid exact: 576 blocks
        int b = i / (DAC * T);
        int r = i % (DAC * T);
        int d = r / T, t = r % T;
        size_t zoff = ((size_t)(b * CH + 256 + d)) * T + t;
        float4 v = *(const float4*)(z + zoff);
        float r0, r1, r2, r3;
        {
            float t0 = (float)tanh((double)v.x); r0 = rintf(t0 * 10.0f);
            float t1 = (float)tanh((double)v.y); r1 = rintf(t1 * 10.0f);
            float t2 = (float)tanh((double)v.z); r2 = rintf(t2 * 10.0f);
            float t3 = (float)tanh((double)v.w); r3 = rintf(t3 * 10.0f);
        }
        *(float4*)(out + zoff) = make_float4(r0, r1, r2, r3);
        size_t co = OFF_CODES + (size_t)(b * DAC + d) * T + t;
        *(float4*)(out + co) = make_float4(r0 + 10.0f, r1 + 10.0f, r2 + 10.0f, r3 + 10.0f);
        size_t ao = OFF_ACQ + (size_t)(b * DAC + d) * T + t;
        out[ao + 0] = r0; out[ao + 1] = r1; out[ao + 2] = r2; out[ao + 3] = r3;
    }
}

// ---------------- MFMA fast argmin + fused 4-split reduce -------------------
// FSPLIT=4 / 512 blocks / sp=bid>>7 / 2 blocks/CU (proven lockstep, 21 MB).
// Main loop frozen since R9. NEW (v12): per-nt arrival counter -- the 4 blocks
// sharing nt (bids nt,+128,+256,+384: all on the SAME XCD, pmx L2-local) sync
// via threadfence+atomic; the last arriver does the 128-row merge, TAU
// flagging, split-exclusion queue pushes, and compacted z-gather into zg.
// Removes the k_reduce2 dispatch. Same s-ascending merge / strict-< logic.
__global__ __launch_bounds__(256, 2) void k_fast(
        const unsigned short* __restrict__ Az, const unsigned short* __restrict__ Bc,
        const float* __restrict__ c2g, float4* pmx,
        const float* __restrict__ z, float* __restrict__ out,
        int* __restrict__ widx, int* __restrict__ cnt, int* __restrict__ list,
        int* __restrict__ qcnt, int* __restrict__ ql, int* __restrict__ ntcnt,
        float* __restrict__ zg) {
    __shared__ __align__(16) unsigned char smem8[65536];   // 2 x 32KB B-tile
    __shared__ float c2s[2048];
    __shared__ int lrow[128], lpos[128];
    __shared__ int lcnt2, lred;

    const int tid = threadIdx.x;
    const int w = tid >> 6, lane = tid & 63;
    const int quad = lane >> 4, c = lane & 15;

    const int sp = blockIdx.x >> 7;          // split 0..3
    const int nt = blockIdx.x & 127;         // row tile
    const int n0 = nt * 128;
    const int kbase = sp * 2048;

    const char* Azb = (const char*)Az;
    const char* Bcb = (const char*)Bc;

    // c2 for this block's 2048 codes -> LDS (visible after prologue sync)
    #pragma unroll
    for (int i = 0; i < 8; i++) c2s[tid + i * 256] = c2g[kbase + tid + i * 256];

    // staging: 8 segs/wave; LDS[code][x] holds global chunk x^(code&7)
    const int hi2 = lane >> 5;
    const char* sq[8];
    #pragma unroll
    for (int q = 0; q < 8; q++) {
        const int seg = w * 8 + q;                       // 0..31, wave-uniform
        const int code = seg * 2 + hi2;
        sq[q] = Bcb + (size_t)(kbase + code) * 512 + (((lane & 31) ^ (code & 7)) << 4);
    }
    auto stage = [&](int t, int buf) {
        unsigned char* base = smem8 + buf * 32768;
        #pragma unroll
        for (int q = 0; q < 8; q++)
            gl_lds16(sq[q] + (size_t)t * 32768, base + (w * 8 + q) * 1024);
    };

    // per-lane tile-invariant LDS read offsets: voff[ks] = c*512 + swz*16
    int voff[8];
    #pragma unroll
    for (int ks = 0; ks < 8; ks++)
        voff[ks] = c * 512 + (((((ks << 2) | quad) ^ (c & 7))) << 4);

    // ---- A fragments: 32 rows/wave resident in VGPRs (64 VGPR) ----
    bf16x8 af[2][8];
    #pragma unroll
    for (int i = 0; i < 2; i++)
        #pragma unroll
        for (int ks = 0; ks < 8; ks++)
            af[i][ks] = *(const bf16x8*)(Azb +
                (size_t)(n0 + w * 32 + i * 16 + c) * 512 + ks * 64 + quad * 16);

    float bm1[8], bm2[8]; int bid[8];
    #pragma unroll
    for (int sl = 0; sl < 8; sl++) { bm1[sl] = FLT_MAX; bm2[sl] = FLT_MAX; bid[sl] = 0x7fffffff; }

    f32x4 accA[2][4], accB[2][4];

    #define MFMA_TILE(BUFC, ACC) do {                                         \
        _Pragma("unroll")                                                     \
        for (int i = 0; i < 2; i++)                                           \
            _Pragma("unroll")                                                 \
            for (int j = 0; j < 4; j++) ACC[i][j] = (f32x4)0.0f;              \
        __builtin_amdgcn_s_setprio(1);                                        \
        _Pragma("unroll")                                                     \
        for (int j = 0; j < 4; j++) {                                         \
            bf16x8 bf[8];                                                     \
            _Pragma("unroll")                                                 \
            for (int ks = 0; ks < 8; ks++)                                    \
                bf[ks] = *(const bf16x8*)(smem8 + voff[ks] +                  \
                                          ((BUFC) * 32768 + j * 8192));       \
            _Pragma("unroll")                                                 \
            for (int ks = 0; ks < 8; ks++) {  /* k ascending */               \
                ACC[0][j] = __builtin_amdgcn_mfma_f32_16x16x32_bf16(af[0][ks], bf[ks], ACC[0][j], 0, 0, 0); \
                ACC[1][j] = __builtin_amdgcn_mfma_f32_16x16x32_bf16(af[1][ks], bf[ks], ACC[1][j], 0, 0, 0); \
            }                                                                 \
        }                                                                     \
        __builtin_amdgcn_s_setprio(0);                                        \
    } while (0)

    auto epilogue = [&](int t, f32x4 (&acc)[2][4]) {   // codes ascending, strict <
        const int k0 = kbase + t * 64;
        #pragma unroll
        for (int j = 0; j < 4; j++) {
            const int kk = k0 + j * 16 + c;
            const float c2v = c2s[t * 64 + j * 16 + c];
            #pragma unroll
            for (int i = 0; i < 2; i++)
                #pragma unroll
                for (int r = 0; r < 4; r++) {
                    float sc = fmaf(-2.0f, acc[i][j][r], c2v);
                    int sl = i * 4 + r;
                    bm2[sl] = __builtin_amdgcn_fmed3f(bm1[sl], sc, bm2[sl]);
                    if (sc < bm1[sl]) { bm1[sl] = sc; bid[sl] = kk; }
                }
        }
    };

    stage(0, 0);
    __syncthreads();                          // stage(0)+c2s+af landed/visible
    stage(1, 1);                              // in flight under tile 0 compute
    MFMA_TILE(0, accA);

    #define FITER(T, BUF, CUR, PRV) do {                                  \
        asm volatile("s_waitcnt vmcnt(0)" ::: "memory");                  \
        __builtin_amdgcn_s_barrier();                                     \
        __builtin_amdgcn_sched_barrier(0);                                \
        if ((T) < 31) stage((T) + 1, (BUF) ^ 1);                          \
        MFMA_TILE(BUF, CUR);                                              \
        epilogue((T) - 1, PRV);                                           \
    } while (0)

    for (int tt = 1; tt < 31; tt += 2) {
        FITER(tt,     1, accB, accA);
        FITER(tt + 1, 0, accA, accB);
    }
    FITER(31, 1, accB, accA);
    epilogue(31, accB);
    #undef FITER
    #undef MFMA_TILE

    // butterfly over the 16 c-lanes (same quad) -- waves own disjoint rows
    #pragma unroll
    for (int mask = 1; mask <= 8; mask <<= 1)
        #pragma unroll
        for (int sl = 0; sl < 8; sl++) {
            float o1 = __shfl_xor(bm1[sl], mask, 64);
            float o2 = __shfl_xor(bm2[sl], mask, 64);
            int   oi = __shfl_xor(bid[sl], mask, 64);
            merge3(bm1[sl], bm2[sl], bid[sl], o1, o2, oi);
        }
    if (c == 0) {
        #pragma unroll
        for (int i = 0; i < 2; i++)
            #pragma unroll
            for (int r = 0; r < 4; r++) {
                int row = w * 32 + i * 16 + quad * 4 + r, sl = i * 4 + r;
                pmx[(size_t)sp * NROWS + n0 + row] =
                    make_float4(bm1[sl], bm2[sl], __int_as_float(bid[sl]), 0.f);
            }
    }

    // ---- fused reduce: last-arriving same-nt block merges the 4 splits ----
    __threadfence();                          // publish pmx device-wide
    if (tid == 0) {
        lred = (atomicAdd(&ntcnt[nt], 1) == 3);
        lcnt2 = 0;
    }
    __syncthreads();
    if (!lred) return;
    __threadfence();                          // acquire: peers' pmx visible
    if (tid < 128) {
        int n = n0 + tid;
        float4 pv[FSPLIT];
        float a1 = FLT_MAX, a2 = FLT_MAX; int ai = 0x7fffffff;
        #pragma unroll
        for (int s = 0; s < FSPLIT; s++) {
            pv[s] = pmx[(size_t)s * NROWS + n];
            merge3(a1, a2, ai, pv[s].x, pv[s].y, __float_as_int(pv[s].z));
        }
        if (a2 - a1 < TAU) {
            int pos = atomicAdd(cnt, 1);
            list[pos] = n;
            int mask = 0;
            #pragma unroll
            for (int s = 0; s < FSPLIT; s++) {
                if (pv[s].x <= a1 + TAU) {
                    mask |= 1 << s;
                    int qp = atomicAdd(&qcnt[s], 1);
                    ql[s * NROWS + qp] = pos;
                }
            }
            widx[n] = ~(pos | (mask << 14));  // marker: resolve in episem
            int l = atomicAdd(&lcnt2, 1);
            lrow[l] = n; lpos[l] = pos;
        } else {
            widx[n] = ai;
            out[OFF_IDX + n] = (float)ai;
        }
    }
    __syncthreads();
    const int lc = lcnt2;
    for (int it2 = 0; it2 < lc; it2++) {
        int pos = lpos[it2];
        if (pos < CAPROWS) {
            int rn = lrow[it2];
            zg[(size_t)pos * D + tid] =
                z[((size_t)((rn >> 11) * CH + tid)) * T + (rn & 2047)];
        }
    }
}

// -------- exact np-pipeline rescue (queued): 32 rows x 512 codes ------------
__global__ __launch_bounds__(256, 2) void k_rescuex(
        const float* __restrict__ z, const float* __restrict__ cb,
        const float* __restrict__ c2, const float* __restrict__ z2,
        const int* __restrict__ list, const int* __restrict__ qcnt,
        const int* __restrict__ ql,
        const float* __restrict__ zg, float2* __restrict__ pr) {
    __shared__ float zs[D][MT + 4];       // 36 KB (pad: aligned f4)
    __shared__ float cs[2][DC][KT + 4];   // 33.8 KB double-buffered
    __shared__ float c2s[512];            // 2 KB
    __shared__ int   ls[MT];
    __shared__ int   lpo[MT];
    __shared__ float z2sh[MT];
    const int tid = threadIdx.x;
    const int tx = tid & 31, ty = tid >> 5;
    const int fs = blockIdx.x & 3, sub = (blockIdx.x >> 2) & 3;
    const int grp = blockIdx.x >> 4;
    const int qc = qcnt[fs];
    const int base = grp * MT;
    if (base >= qc) return;
    const int nr = min(MT, qc - base);
    const int kbase = fs * 2048 + sub * 512;
    const int rs = fs * 4 + sub;
    const int kl = tid & 127, half = tid >> 7;

    if (tid < MT) {
        int qi = base + ((tid < nr) ? tid : (nr - 1));
        int pos = ql[fs * NROWS + qi];
        int n = list[pos];
        ls[tid] = n; lpo[tid] = pos;
        z2sh[tid] = z2[n];
    }
    #pragma unroll
    for (int i = 0; i < 2; i++)
        c2s[tid + i * 256] = c2[kbase + tid + i * 256];

    float4 rv0, rv1, rv2, rv3;
    auto ldchunk = [&](int ch) {
        const int k0 = kbase + (ch >> 3) * KT, dcc = (ch & 7) * DC;
        const float4* src = (const float4*)(cb + (size_t)(k0 + kl) * D + dcc + half * 16);
        rv0 = src[0]; rv1 = src[1]; rv2 = src[2]; rv3 = src[3];
    };
    auto wrchunk = [&](int b) {
        const int dl = half * 16;
        cs[b][dl + 0][kl] = rv0.x; cs[b][dl + 1][kl] = rv0.y;
        cs[b][dl + 2][kl] = rv0.z; cs[b][dl + 3][kl] = rv0.w;
        cs[b][dl + 4][kl] = rv1.x; cs[b][dl + 5][kl] = rv1.y;
        cs[b][dl + 6][kl] = rv1.z; cs[b][dl + 7][kl] = rv1.w;
        cs[b][dl + 8][kl] = rv2.x; cs[b][dl + 9][kl] = rv2.y;
        cs[b][dl + 10][kl] = rv2.z; cs[b][dl + 11][kl] = rv2.w;
        cs[b][dl + 12][kl] = rv3.x; cs[b][dl + 13][kl] = rv3.y;
        cs[b][dl + 14][kl] = rv3.z; cs[b][dl + 15][kl] = rv3.w;
    };

    ldchunk(0);                               // in flight under zs fill
    __syncthreads();                          // ls/lpo visible
    for (int i = tid; i < MT * 64; i += 256) {
        int r = i >> 6, dq = (i & 63) << 2;
        int po = lpo[r];
        if (po < CAPROWS) {
            float4 v = *(const float4*)(zg + (size_t)po * D + dq);
            zs[dq + 0][r] = v.x; zs[dq + 1][r] = v.y;
            zs[dq + 2][r] = v.z; zs[dq + 3][r] = v.w;
        } else {                              // overflow fallback: scattered z
            int n = ls[r];
            #pragma unroll
            for (int e = 0; e < 4; e++)
                zs[dq + e][r] = z[((size_t)((n >> 11) * CH + dq + e)) * T + (n & 2047)];
        }
    }
    __syncthreads();
    wrchunk(0);
    ldchunk(1);
    asm volatile("s_waitcnt lgkmcnt(0)" ::: "memory");
    __builtin_amdgcn_s_barrier();
    __builtin_amdgcn_sched_barrier(0);

    float z2r[4];
    #pragma unroll
    for (int i = 0; i < 4; i++) z2r[i] = z2sh[ty * 4 + i];

    float m1[4]; int bi[4];
    #pragma unroll
    for (int i = 0; i < 4; i++) { m1[i] = FLT_MAX; bi[i] = 0x7fffffff; }
    float acc[4][4] = {};

    const int NCH = (512 / KT) * (D / DC);    // 32 chunks
    for (int ch = 0; ch < NCH; ch++) {
        const int b = ch & 1;
        const int dcc = (ch & 7) * DC;
        #pragma unroll 8
        for (int d = 0; d < DC; d++) {
            const float4 zf = *(const float4*)&zs[dcc + d][ty * 4];
            const float4 cf = *(const float4*)&cs[b][d][tx * 4];
            const float za[4] = {zf.x, zf.y, zf.z, zf.w};
            const float ca[4] = {cf.x, cf.y, cf.z, cf.w};
            #pragma unroll
            for (int i = 0; i < 4; i++)
                #pragma unroll
                for (int j = 0; j < 4; j++)
                    acc[i][j] = fmaf(za[i], ca[j], acc[i][j]);
        }
        if ((ch & 7) == 7) {
            const int koff = (ch >> 3) * KT;
            #pragma unroll
            for (int j = 0; j < 4; j++) {
                int kk = kbase + koff + tx * 4 + j;
                float c2v = c2s[koff + tx * 4 + j];
                #pragma unroll
                for (int i = 0; i < 4; i++) {
                    float tpre = z2r[i] - 2.0f * acc[i][j];   // np combine order
                    float s = tpre + c2v;
                    if (s < m1[i]) { m1[i] = s; bi[i] = kk; } // strict <
                }
            }
            #pragma unroll
            for (int i = 0; i < 4; i++)
                #pragma unroll
                for (int j = 0; j < 4; j++) acc[i][j] = 0.0f;
        }
        if (ch < NCH - 1) {
            __syncthreads();
            wrchunk(b ^ 1);
            if (ch < NCH - 2) ldchunk(ch + 2);
            asm volatile("s_waitcnt lgkmcnt(0)" ::: "memory");
            __builtin_amdgcn_s_barrier();
            __builtin_amdgcn_sched_barrier(0);
        }
    }
    __syncthreads();
    float* rm1 = (float*)zs;
    int*   rix = (int*)(rm1 + MT * 32);
    #pragma unroll
    for (int i = 0; i < 4; i++) {
        int slot = (ty * 4 + i) * 32 + tx;
        rm1[slot] = m1[i]; rix[slot] = bi[i];
    }
    __syncthreads();
    if (tid < MT) {
        float a1 = FLT_MAX; int ai = 0x7fffffff;
        for (int t = 0; t < 32; t++) {
            float b1 = rm1[tid * 32 + t]; int bidx = rix[tid * 32 + t];
            if (b1 < a1 || (b1 == a1 && bidx < ai)) { a1 = b1; ai = bidx; }
        }
        if (tid < nr)
            pr[(size_t)rs * NROWS + lpo[tid]] = make_float2(a1, __int_as_float(ai));
    }
}

// ---------------- fallback exact fp32 GEMM-argmin (Round-3, passing) --------
__global__ __launch_bounds__(256) void k_exact(
        const float* __restrict__ z, const float* __restrict__ cb,
        const float* __restrict__ c2, const float* __restrict__ z2,
        float2* __restrict__ part) {
    __shared__ float zs[D][MT];
    __shared__ float cs[DC][KT + 4];
    const int tid = threadIdx.x;
    const int tx = tid & 31, ty = tid >> 5;
    const int n0 = blockIdx.x * MT;
    const int bb = n0 >> 11, t0 = n0 & 2047;
    const int kbase = blockIdx.y * (K / NSPLIT);
    for (int i = tid; i < D * (MT / 4); i += 256) {
        int d = i >> 3, tg = i & 7;
        float4 v = *(const float4*)(z + ((size_t)(bb * CH + d)) * T + t0 + tg * 4);
        *(float4*)&zs[d][tg * 4] = v;
    }
    float z2r[4];
    #pragma unroll
    for (int i = 0; i < 4; i++) z2r[i] = z2[n0 + ty * 4 + i];
    float m1[4]; int bi[4];
    #pragma unroll
    for (int i = 0; i < 4; i++) { m1[i] = FLT_MAX; bi[i] = 0x7fffffff; }
    for (int ktt = 0; ktt < K / NSPLIT; ktt += KT) {
        const int k0 = kbase + ktt;
        float acc[4][4] = {};
        for (int dc = 0; dc < D; dc += DC) {
            __syncthreads();
            {
                int kl = tid & 127, half = tid >> 7;
                const float4* src = (const float4*)(cb + (size_t)(k0 + kl) * D + dc + half * 16);
                #pragma unroll
                for (int j = 0; j < 4; j++) {
                    float4 v = src[j];
                    int dl = half * 16 + j * 4;
                    cs[dl + 0][kl] = v.x; cs[dl + 1][kl] = v.y;
                    cs[dl + 2][kl] = v.z; cs[dl + 3][kl] = v.w;
                }
            }
            __syncthreads();
            #pragma unroll 8
            for (int d = 0; d < DC; d++) {
                const float4 zf = *(const float4*)&zs[dc + d][ty * 4];
                const float4 cf = *(const float4*)&cs[d][tx * 4];
                const float za[4] = {zf.x, zf.y, zf.z, zf.w};
                const float ca[4] = {cf.x, cf.y, cf.z, cf.w};
                #pragma unroll
                for (int i = 0; i < 4; i++)
                    #pragma unroll
                    for (int j = 0; j < 4; j++)
                        acc[i][j] = fmaf(za[i], ca[j], acc[i][j]);
            }
        }
        #pragma unroll
        for (int j = 0; j < 4; j++) {
            int kk = k0 + tx * 4 + j;
            float c2v = c2[kk];
            #pragma unroll
            for (int i = 0; i < 4; i++) {
                float tpre = z2r[i] - 2.0f * acc[i][j];
                float s = tpre + c2v;
                if (s < m1[i]) { m1[i] = s; bi[i] = kk; }
            }
        }
    }
    __syncthreads();
    float* rm1 = (float*)zs;
    int*   rix = (int*)(rm1 + MT * 32);
    #pragma unroll
    for (int i = 0; i < 4; i++) {
        int slot = (ty * 4 + i) * 32 + tx;
        rm1[slot] = m1[i]; rix[slot] = bi[i];
    }
    __syncthreads();
    if (tid < MT) {
        float a1 = FLT_MAX; int ai = 0x7fffffff;
        for (int t = 0; t < 32; t++) {
            float b1 = rm1[tid * 32 + t]; int bidx = rix[tid * 32 + t];
            if (b1 < a1 || (b1 == a1 && bidx < ai)) { a1 = b1; ai = bidx; }
        }
        part[(size_t)(n0 + tid) * NSPLIT + blockIdx.y] = make_float2(a1, __int_as_float(ai));
    }
}

__global__ void k_reduce(const float2* __restrict__ part, int* __restrict__ widx,
                         float* __restrict__ out) {
    int n = blockIdx.x * 256 + threadIdx.x;
    float a1 = FLT_MAX; int ai = 0x7fffffff;
    #pragma unroll
    for (int s = 0; s < NSPLIT; s++) {
        float2 p = part[(size_t)n * NSPLIT + s];
        float b1 = p.x; int bidx = __float_as_int(p.y);
        if (b1 < a1 || (b1 == a1 && bidx < ai)) { a1 = b1; ai = bidx; }
    }
    widx[n] = ai;
    out[OFF_IDX + n] = (float)ai;
}

// ------- epilogue: gather z_q + loss partials; masked rescue-split merge ----
// (R10-measured body: scalar main loop, separate k_loss)
__global__ __launch_bounds__(256) void k_episem(
        const float* __restrict__ z, const float* __restrict__ cb,
        const int* __restrict__ widx, const float2* __restrict__ pr,
        float* __restrict__ out, double* __restrict__ lossp) {
    __shared__ int qidx[32];
    __shared__ float qs[32][260];
    __shared__ double wsum[4];
    const int tid = threadIdx.x;
    const int bb = blockIdx.x >> 6;
    const int t0 = (blockIdx.x & 63) * 32;
    if (tid < 32) {
        int n = bb * T + t0 + tid;
        int wv = widx[n];
        if (wv < 0) {
            unsigned u = ~wv;
            int pos = u & 16383;
            int mask = (u >> 14) & 15;
            float a1 = FLT_MAX; int ai = 0x7fffffff;
            #pragma unroll
            for (int s = 0; s < RSPLIT; s++) {
                if ((mask >> (s >> 2)) & 1) {
                    float2 p = pr[(size_t)s * NROWS + pos];
                    float v = p.x; int ix = __float_as_int(p.y);
                    if (v < a1 || (v == a1 && ix < ai)) { a1 = v; ai = ix; }
                }
            }
            wv = ai;
            out[OFF_IDX + n] = (float)ai;
        }
        qidx[tid] = wv;
    }
    __syncthreads();
    for (int i = tid; i < 32 * 64; i += 256) {
        int tl = i >> 6, lanee = i & 63;
        float4 v = *(const float4*)(cb + (size_t)qidx[tl] * D + lanee * 4);
        *(float4*)&qs[tl][lanee * 4] = v;
    }
    __syncthreads();
    double ls = 0.0;
    for (int it = 0; it < 32; it++) {
        int d = it * 8 + (tid >> 5);
        int tl = tid & 31;
        size_t ga = ((size_t)(bb * CH + d)) * T + t0 + tl;
        float q = qs[tl][d];
        float e = q - z[ga];
        out[ga] = q;
        ls += (double)e * (double)e;
    }
    #pragma unroll
    for (int off = 32; off; off >>= 1) ls += __shfl_down(ls, off, 64);
    if ((tid & 63) == 0) wsum[tid >> 6] = ls;
    __syncthreads();
    if (tid == 0) lossp[blockIdx.x] = wsum[0] + wsum[1] + wsum[2] + wsum[3];
}

// ------------- loss finalize (1 block) -------------
__global__ void k_loss(const double* __restrict__ lossp, float* __restrict__ out) {
    __shared__ double sm[256];
    int tid = threadIdx.x;
    sm[tid] = lossp[tid] + lossp[tid + 256];
    __syncthreads();
    for (int off = 128; off; off >>= 1) {
        if (tid < off) sm[tid] += sm[tid + off];
        __syncthreads();
    }
    if (tid == 0) out[OFF_LOSS] = (float)(1.1 * sm[0] / (double)(BQ * D * T));
}

// ------------- fallback epilogue variants (fallback path only) -------------
__global__ __launch_bounds__(256) void k_episemf(
        const float* __restrict__ z, const float* __restrict__ cb,
        const int* __restrict__ widx, float* __restrict__ out, double* __restrict__ lossp) {
    __shared__ int qidx[32];
    __shared__ float qs[32][260];
    __shared__ double wsum[4];
    const int tid = threadIdx.x;
    const int bb = blockIdx.x >> 6;
    const int t0 = (blockIdx.x & 63) * 32;
    if (tid < 32) qidx[tid] = widx[bb * T + t0 + tid];
    __syncthreads();
    for (int i = tid; i < 32 * 64; i += 256) {
        int tl = i >> 6, lanee = i & 63;
        float4 v = *(const float4*)(cb + (size_t)qidx[tl] * D + lanee * 4);
        *(float4*)&qs[tl][lanee * 4] = v;
    }
    __syncthreads();
    double ls = 0.0;
    for (int it = 0; it < 32; it++) {
        int d = it * 8 + (tid >> 5);
        int tl = tid & 31;
        size_t ga = ((size_t)(bb * CH + d)) * T + t0 + tl;
        float q = qs[tl][d];
        float e = q - z[ga];
        out[ga] = q;
        ls += (double)e * (double)e;
    }
    #pragma unroll
    for (int off = 32; off; off >>= 1) ls += __shfl_down(ls, off, 64);
    if ((tid & 63) == 0) wsum[tid >> 6] = ls;
    __syncthreads();
    if (tid == 0) lossp[blockIdx.x] = wsum[0] + wsum[1] + wsum[2] + wsum[3];
}

__global__ void k_epiac(const float* __restrict__ z, const double* __restrict__ lossp,
                        float* __restrict__ out) {
    __shared__ double sm[256];
    int i = (blockIdx.x * 256 + threadIdx.x) * 4;   // grid exact: no early return
    int b = i / (DAC * T);
    int r = i % (DAC * T);
    int d = r / T, t = r % T;
    size_t zoff = ((size_t)(b * CH + 256 + d)) * T + t;
    float4 v = *(const float4*)(z + zoff);
    float r0, r1, r2, r3;
    {
        float t0 = (float)tanh((double)v.x); r0 = rintf(t0 * 10.0f);
        float t1 = (float)tanh((double)v.y); r1 = rintf(t1 * 10.0f);
        float t2 = (float)tanh((double)v.z); r2 = rintf(t2 * 10.0f);
        float t3 = (float)tanh((double)v.w); r3 = rintf(t3 * 10.0f);
    }
    *(float4*)(out + zoff) = make_float4(r0, r1, r2, r3);
    size_t co = OFF_CODES + (size_t)(b * DAC + d) * T + t;
    *(float4*)(out + co) = make_float4(r0 + 10.0f, r1 + 10.0f, r2 + 10.0f, r3 + 10.0f);
    size_t ao = OFF_ACQ + (size_t)(b * DAC + d) * T + t;
    out[ao + 0] = r0; out[ao + 1] = r1; out[ao + 2] = r2; out[ao + 3] = r3;
    if (blockIdx.x == 0) {
        int tid = threadIdx.x;
        sm[tid] = lossp[tid] + lossp[tid + 256];
        __syncthreads();
        for (int off = 128; off; off >>= 1) {
            if (tid < off) sm[tid] += sm[tid + off];
            __syncthreads();
        }
        if (tid == 0) out[OFF_LOSS] = (float)(1.1 * sm[0] / (double)(BQ * D * T));
    }
}

extern "C" void kernel_launch(void* const* d_in, const int* in_sizes, int n_in,
                              void* d_out, int out_size, void* d_ws, size_t ws_size,
                              hipStream_t stream) {
    const float* z  = (const float*)d_in[0];
    const float* cb = (const float*)d_in[1];
    float* out = (float*)d_out;
    char* ws = (char*)d_ws;

    if (ws_size >= (size_t)WN_NEED) {
        float*  c2    = (float*)(ws + WN_C2);
        float*  z2    = (float*)(ws + WN_Z2);
        int*    cnt   = (int*)(ws + WN_CNT);
        int*    list  = (int*)(ws + WN_LIST);
        double* lossp = (double*)(ws + WN_LOSS);
        int*    widx  = (int*)(ws + WN_WIDX);
        int*    qcnt  = (int*)(ws + WN_QCNT);
        int*    ntc   = (int*)(ws + WN_NTC);
        int*    ql    = (int*)(ws + WN_QL);
        float4* pmx   = (float4*)(ws + WN_PMX);
        unsigned short* Az = (unsigned short*)(ws + WN_AZ);
        unsigned short* Bc = (unsigned short*)(ws + WN_BC);
        float*  zg    = (float*)(ws + WN_ZG);    // private region (no alias)
        float2* pr    = (float2*)(ws + WN_PR);   // aliases pmx (dead after k_fast tail)

        hipLaunchKernelGGL(k_prep,    dim3(K / 4 + 512 + BQ * DAC * T / 1024), dim3(256), 0, stream,
                           z, cb, Az, Bc, c2, z2, cnt, qcnt, ntc, out);
        hipLaunchKernelGGL(k_fast,    dim3(128 * FSPLIT), dim3(256), 0, stream,
                           Az, Bc, c2, pmx, z, out, widx, cnt, list, qcnt, ql, ntc, zg);
        hipLaunchKernelGGL(k_rescuex, dim3((NROWS / MT) * RSPLIT), dim3(256), 0, stream,
                           z, cb, c2, z2, list, qcnt, ql, zg, pr);
        hipLaunchKernelGGL(k_episem,  dim3(BQ * (T / 32)), dim3(256), 0, stream,
                           z, cb, widx, pr, out, lossp);
        hipLaunchKernelGGL(k_loss,    dim3(1),            dim3(256), 0, stream, lossp, out);
    } else {
        float*  c2    = (float*)(ws + WS_C2);
        float*  z2    = (float*)(ws + WS_Z2);
        float2* part  = (float2*)(ws + WS_PART);
        int*    widx  = (int*)(ws + WS_IDX);
        double* lossp = (double*)(ws + WS_LOSS);
        hipLaunchKernelGGL(k_c2pw,   dim3(K / 256),            dim3(256), 0, stream, cb, c2);
        hipLaunchKernelGGL(k_z2pw,   dim3(NROWS / 256),        dim3(256), 0, stream, z, z2);
        hipLaunchKernelGGL(k_exact,  dim3(NROWS / MT, NSPLIT), dim3(256), 0, stream, z, cb, c2, z2, part);
        hipLaunchKernelGGL(k_reduce, dim3(NROWS / 256),        dim3(256), 0, stream, part, widx, out);
        hipLaunchKernelGGL(k_episemf, dim3(BQ * (T / 32)),     dim3(256), 0, stream, z, cb, widx, out, lossp);
        hipLaunchKernelGGL(k_epiac,  dim3(BQ * DAC * T / 1024), dim3(256), 0, stream, z, lossp, out);
    }
}

// Round 13
// 254.349 us; speedup vs baseline: 1.1581x; 1.1581x over previous
//
#include <hip/hip_runtime.h>
#include <cfloat>
#include <math.h>

// Problem constants
#define BQ 8
#define T 2048
#define D 256
#define DAC 36
#define CH 292
#define K 8192
#define NROWS (BQ*T)          // 16384
#define TAU 1e-3f             // single-bf16-pass error bound + np noise
#define FSPLIT 4              // k-splits in fast kernel (2048 codes each)
#define RSPLIT 16             // k-splits in rescue (512 codes each)
#define CAPROWS 8192          // zg capacity (aliases dead Az region)

// Output offsets (floats, reference return order)
#define OFF_IDX   (BQ*CH*T)
#define OFF_CODES (OFF_IDX + NROWS)
#define OFF_LOSS  (OFF_CODES + BQ*DAC*T)
#define OFF_ACQ   (OFF_LOSS + 1)

// ---------------- MFMA-path ws layout, bytes ----------------
#define WN_C2    0                            // float[K]            32 KB
#define WN_Z2    32768                        // float[NROWS]        64 KB
#define WN_CNT   98304                        // int (flag count)
#define WN_LIST  98560                        // int[NROWS]          64 KB
#define WN_LOSS  164096                       // double[512]          4 KB
#define WN_WIDX  168192                       // int[NROWS]          64 KB
#define WN_QCNT  233728                       // int[4] (gap before PMX)
#define WN_PMX   262144                       // float4[FSPLIT*NROWS] = 1 MB
#define WN_PR    262144                       // float2[RSPLIT*NROWS] = 2 MB (alias, pmx dead)
#define WN_AZ    2359296                      // ushort[16384][256] = 8 MB (hi only)
#define WN_ZG    2359296                      // float[8192][256] = 8 MB (alias AZ)
#define WN_BC    10747904                     // ushort[8192][256]  = 4 MB (hi only)
#define WN_QL    14942208                     // int[4][NROWS] = 256 KB (queues)
#define WN_NEED  15204352

// ---------------- old (fallback) ws layout ----------------
#define WS_C2    0
#define WS_Z2    32768
#define WS_PART  131072
#define WS_IDX   655360
#define WS_LOSS  720896
#define MT 32
#define KT 128
#define DC 32
#define NSPLIT 4

typedef float f32x4 __attribute__((ext_vector_type(4)));
typedef __bf16 bf16x8 __attribute__((ext_vector_type(8)));
typedef __attribute__((address_space(1))) const unsigned int gu32;
typedef __attribute__((address_space(3))) unsigned int lu32;

__device__ inline void gl_lds16(const void* gp, void* lp) {
    __builtin_amdgcn_global_load_lds((gu32*)gp, (lu32*)lp, 16, 0, 0);
}

__device__ inline unsigned short f2bf(float x) {   // RNE, finite inputs
    unsigned u = __float_as_uint(x);
    return (unsigned short)((u + 0x7fffu + ((u >> 16) & 1u)) >> 16);
}

__device__ inline void merge3(float& m1, float& m2, int& mi, float o1, float o2, int oi) {
    if (o1 < m1 || (o1 == m1 && oi < mi)) { m2 = fminf(m1, o2); m1 = o1; mi = oi; }
    else                                  { m2 = fminf(m2, o1); }
}

// ---- numpy pairwise-sum emulation (AVX512 W=16, n=256) ----
template <typename F>
__device__ float np_pairwise256_sq(F ld) {
    float S[2];
    #pragma unroll
    for (int h = 0; h < 2; h++) {
        int base = h * 128;
        float v[16];
        #pragma unroll
        for (int l = 0; l < 16; l++) {
            float q[8];
            #pragma unroll
            for (int j = 0; j < 8; j++) { float x = ld(base + j * 16 + l); q[j] = x * x; }
            v[l] = ((q[0] + q[1]) + (q[2] + q[3])) + ((q[4] + q[5]) + (q[6] + q[7]));
        }
        float t1[8], t2[4], t3[2];
        #pragma unroll
        for (int l = 0; l < 8; l++) t1[l] = v[l] + v[l + 8];
        #pragma unroll
        for (int l = 0; l < 4; l++) t2[l] = t1[l] + t1[l + 4];
        t3[0] = t2[0] + t2[2]; t3[1] = t2[1] + t2[3];
        S[h] = t3[0] + t3[1];
    }
    return S[0] + S[1];
}

// fallback-path helpers
__global__ void k_c2pw(const float* __restrict__ cb, float* __restrict__ c2) {
    int k = blockIdx.x * 256 + threadIdx.x;
    const float* row = cb + (size_t)k * D;
    c2[k] = np_pairwise256_sq([&](int d) { return row[d]; });
}

__global__ void k_z2pw(const float* __restrict__ z, float* __restrict__ z2) {
    int n = blockIdx.x * 256 + threadIdx.x;
    int b = n >> 11, t = n & 2047;
    const float* base = z + (size_t)b * CH * T + t;
    z2[n] = np_pairwise256_sq([&](int d) { return base[(size_t)d * T]; });
}

// ------ fused prep: [0,2048) codebook | [2048,2560) z-prep | [2560,3136) ac -
__global__ __launch_bounds__(256) void k_prep(const float* __restrict__ z,
        const float* __restrict__ cb, unsigned short* __restrict__ Az,
        unsigned short* __restrict__ Bc, float* __restrict__ c2,
        float* __restrict__ z2, int* __restrict__ cnt, int* __restrict__ qcnt,
        float* __restrict__ out) {
    __shared__ float zt[32][260];
    const int tid = threadIdx.x;
    if ((int)blockIdx.x < (K / 4)) {
        const int w = tid >> 6, l = tid & 63;
        const int k = blockIdx.x * 4 + w;
        float4 v = *(const float4*)(cb + (size_t)k * D + l * 4);
        *(float4*)&zt[w][l * 4] = v;
        float fa[4] = {v.x, v.y, v.z, v.w};
        unsigned short hh[4];
        #pragma unroll
        for (int e = 0; e < 4; e++) hh[e] = f2bf(fa[e]);
        *(uint2*)(Bc + (size_t)k * 256 + l * 4) = *(uint2*)hh;
        __syncthreads();
        if (tid < 4) {
            int kk = blockIdx.x * 4 + tid;
            c2[kk] = np_pairwise256_sq([&](int d) { return zt[tid][d]; });
        }
        if (blockIdx.x == 0) {
            if (tid == 0) *cnt = 0;
            if (tid < 4) qcnt[tid] = 0;
        }
    } else if ((int)blockIdx.x < (K / 4) + 512) {
        const int bb = blockIdx.x - (K / 4);
        const int b = bb >> 6, t0 = (bb & 63) * 32;
        for (int i = tid; i < 2048; i += 256) {
            int d = i >> 3, tq = (i & 7) * 4;
            float4 v = *(const float4*)(z + (size_t)(b * CH + d) * T + t0 + tq);
            zt[tq + 0][d] = v.x; zt[tq + 1][d] = v.y;
            zt[tq + 2][d] = v.z; zt[tq + 3][d] = v.w;
        }
        __syncthreads();
        const int t = tid >> 3, c8 = tid & 7;
        unsigned short* rowp = Az + (size_t)(b * 2048 + t0 + t) * 256;
        #pragma unroll
        for (int li = 0; li < 4; li++) {
            int u = c8 + 8 * li;                 // 16B chunk index 0..31
            int dbase = u * 8;
            float f[8];
            *(float4*)&f[0] = *(float4*)&zt[t][dbase];
            *(float4*)&f[4] = *(float4*)&zt[t][dbase + 4];
            unsigned short h[8];
            #pragma unroll
            for (int e = 0; e < 8; e++) h[e] = f2bf(f[e]);
            *(uint4*)(rowp + u * 8) = *(uint4*)h;
        }
        if (tid < 32)
            z2[b * 2048 + t0 + tid] = np_pairwise256_sq([&](int d) { return zt[tid][d]; });
    } else {
        // ---- ac path (independent of VQ) ----
        const int ab = blockIdx.x - ((K / 4) + 512);
        int i = (ab * 256 + tid) * 4;            // grid exact: 576 blocks
        int b = i / (DAC * T);
        int r = i % (DAC * T);
        int d = r / T, t = r % T;
        size_t zoff = ((size_t)(b * CH + 256 + d)) * T + t;
        float4 v = *(const float4*)(z + zoff);
        float r0, r1, r2, r3;
        {
            float t0 = (float)tanh((double)v.x); r0 = rintf(t0 * 10.0f);
            float t1 = (float)tanh((double)v.y); r1 = rintf(t1 * 10.0f);
            float t2 = (float)tanh((double)v.z); r2 = rintf(t2 * 10.0f);
            float t3 = (float)tanh((double)v.w); r3 = rintf(t3 * 10.0f);
        }
        *(float4*)(out + zoff) = make_float4(r0, r1, r2, r3);
        size_t co = OFF_CODES + (size_t)(b * DAC + d) * T + t;
        *(float4*)(out + co) = make_float4(r0 + 10.0f, r1 + 10.0f, r2 + 10.0f, r3 + 10.0f);
        size_t ao = OFF_ACQ + (size_t)(b * DAC + d) * T + t;
        out[ao + 0] = r0; out[ao + 1] = r1; out[ao + 2] = r2; out[ao + 3] = r3;
    }
}

// ---------------- MFMA fast argmin: single bf16 pass (register-resident A) --
// FSPLIT=4 / 512 blocks / sp=bid>>7 / 2 blocks/CU (proven lockstep, 21 MB).
// (frozen since R9: med3 epilogue, setprio MFMA cluster, voff immediates)
__global__ __launch_bounds__(256, 2) void k_fast(
        const unsigned short* __restrict__ Az, const unsigned short* __restrict__ Bc,
        const float* __restrict__ c2g, float4* __restrict__ pmx) {
    __shared__ __align__(16) unsigned char smem8[65536];   // 2 x 32KB B-tile
    __shared__ float c2s[2048];

    const int tid = threadIdx.x;
    const int w = tid >> 6, lane = tid & 63;
    const int quad = lane >> 4, c = lane & 15;

    const int sp = blockIdx.x >> 7;          // split 0..3
    const int nt = blockIdx.x & 127;         // row tile
    const int n0 = nt * 128;
    const int kbase = sp * 2048;

    const char* Azb = (const char*)Az;
    const char* Bcb = (const char*)Bc;

    // c2 for this block's 2048 codes -> LDS (visible after prologue sync)
    #pragma unroll
    for (int i = 0; i < 8; i++) c2s[tid + i * 256] = c2g[kbase + tid + i * 256];

    // staging: 8 segs/wave; LDS[code][x] holds global chunk x^(code&7)
    const int hi2 = lane >> 5;
    const char* sq[8];
    #pragma unroll
    for (int q = 0; q < 8; q++) {
        const int seg = w * 8 + q;                       // 0..31, wave-uniform
        const int code = seg * 2 + hi2;
        sq[q] = Bcb + (size_t)(kbase + code) * 512 + (((lane & 31) ^ (code & 7)) << 4);
    }
    auto stage = [&](int t, int buf) {
        unsigned char* base = smem8 + buf * 32768;
        #pragma unroll
        for (int q = 0; q < 8; q++)
            gl_lds16(sq[q] + (size_t)t * 32768, base + (w * 8 + q) * 1024);
    };

    // per-lane tile-invariant LDS read offsets: voff[ks] = c*512 + swz*16
    int voff[8];
    #pragma unroll
    for (int ks = 0; ks < 8; ks++)
        voff[ks] = c * 512 + (((((ks << 2) | quad) ^ (c & 7))) << 4);

    // ---- A fragments: 32 rows/wave resident in VGPRs (64 VGPR) ----
    bf16x8 af[2][8];
    #pragma unroll
    for (int i = 0; i < 2; i++)
        #pragma unroll
        for (int ks = 0; ks < 8; ks++)
            af[i][ks] = *(const bf16x8*)(Azb +
                (size_t)(n0 + w * 32 + i * 16 + c) * 512 + ks * 64 + quad * 16);

    float bm1[8], bm2[8]; int bid[8];
    #pragma unroll
    for (int sl = 0; sl < 8; sl++) { bm1[sl] = FLT_MAX; bm2[sl] = FLT_MAX; bid[sl] = 0x7fffffff; }

    f32x4 accA[2][4], accB[2][4];

    #define MFMA_TILE(BUFC, ACC) do {                                         \
        _Pragma("unroll")                                                     \
        for (int i = 0; i < 2; i++)                                           \
            _Pragma("unroll")                                                 \
            for (int j = 0; j < 4; j++) ACC[i][j] = (f32x4)0.0f;              \
        __builtin_amdgcn_s_setprio(1);                                        \
        _Pragma("unroll")                                                     \
        for (int j = 0; j < 4; j++) {                                         \
            bf16x8 bf[8];                                                     \
            _Pragma("unroll")                                                 \
            for (int ks = 0; ks < 8; ks++)                                    \
                bf[ks] = *(const bf16x8*)(smem8 + voff[ks] +                  \
                                          ((BUFC) * 32768 + j * 8192));       \
            _Pragma("unroll")                                                 \
            for (int ks = 0; ks < 8; ks++) {  /* k ascending */               \
                ACC[0][j] = __builtin_amdgcn_mfma_f32_16x16x32_bf16(af[0][ks], bf[ks], ACC[0][j], 0, 0, 0); \
                ACC[1][j] = __builtin_amdgcn_mfma_f32_16x16x32_bf16(af[1][ks], bf[ks], ACC[1][j], 0, 0, 0); \
            }                                                                 \
        }                                                                     \
        __builtin_amdgcn_s_setprio(0);                                        \
    } while (0)

    auto epilogue = [&](int t, f32x4 (&acc)[2][4]) {   // codes ascending, strict <
        const int k0 = kbase + t * 64;
        #pragma unroll
        for (int j = 0; j < 4; j++) {
            const int kk = k0 + j * 16 + c;
            const float c2v = c2s[t * 64 + j * 16 + c];
            #pragma unroll
            for (int i = 0; i < 2; i++)
                #pragma unroll
                for (int r = 0; r < 4; r++) {
                    float sc = fmaf(-2.0f, acc[i][j][r], c2v);
                    int sl = i * 4 + r;
                    bm2[sl] = __builtin_amdgcn_fmed3f(bm1[sl], sc, bm2[sl]);
                    if (sc < bm1[sl]) { bm1[sl] = sc; bid[sl] = kk; }
                }
        }
    };

    stage(0, 0);
    __syncthreads();                          // stage(0)+c2s+af landed/visible
    stage(1, 1);                              // in flight under tile 0 compute
    MFMA_TILE(0, accA);

    #define FITER(T, BUF, CUR, PRV) do {                                  \
        asm volatile("s_waitcnt vmcnt(0)" ::: "memory");                  \
        __builtin_amdgcn_s_barrier();                                     \
        __builtin_amdgcn_sched_barrier(0);                                \
        if ((T) < 31) stage((T) + 1, (BUF) ^ 1);                          \
        MFMA_TILE(BUF, CUR);                                              \
        epilogue((T) - 1, PRV);                                           \
    } while (0)

    for (int tt = 1; tt < 31; tt += 2) {
        FITER(tt,     1, accB, accA);
        FITER(tt + 1, 0, accA, accB);
    }
    FITER(31, 1, accB, accA);
    epilogue(31, accB);
    #undef FITER
    #undef MFMA_TILE

    // butterfly over the 16 c-lanes (same quad) -- waves own disjoint rows
    #pragma unroll
    for (int mask = 1; mask <= 8; mask <<= 1)
        #pragma unroll
        for (int sl = 0; sl < 8; sl++) {
            float o1 = __shfl_xor(bm1[sl], mask, 64);
            float o2 = __shfl_xor(bm2[sl], mask, 64);
            int   oi = __shfl_xor(bid[sl], mask, 64);
            merge3(bm1[sl], bm2[sl], bid[sl], o1, o2, oi);
        }
    if (c == 0) {
        #pragma unroll
        for (int i = 0; i < 2; i++)
            #pragma unroll
            for (int r = 0; r < 4; r++) {
                int row = w * 32 + i * 16 + quad * 4 + r, sl = i * 4 + r;
                pmx[(size_t)sp * NROWS + n0 + row] =
                    make_float4(bm1[sl], bm2[sl], __int_as_float(bid[sl]), 0.f);
            }
    }
}

// ------- reduce 4 k-splits; split-exclusion queues; fused z-gather ----------
__global__ __launch_bounds__(256) void k_reduce2(const float4* __restrict__ pmx,
                          int* __restrict__ widx,
                          int* __restrict__ cnt, int* __restrict__ list,
                          float* __restrict__ out, const float* __restrict__ z,
                          float* __restrict__ zg, int* __restrict__ qcnt,
                          int* __restrict__ ql) {
    __shared__ int lrow[256], lpos[256];
    __shared__ int lcnt;
    const int tid = threadIdx.x;
    if (tid == 0) lcnt = 0;
    __syncthreads();
    int n = blockIdx.x * 256 + tid;
    float4 pv[FSPLIT];
    float a1 = FLT_MAX, a2 = FLT_MAX; int ai = 0x7fffffff;
    #pragma unroll
    for (int s = 0; s < FSPLIT; s++) {
        pv[s] = pmx[(size_t)s * NROWS + n];
        merge3(a1, a2, ai, pv[s].x, pv[s].y, __float_as_int(pv[s].z));
    }
    if (a2 - a1 < TAU) {
        int pos = atomicAdd(cnt, 1);
        list[pos] = n;
        int mask = 0;
        #pragma unroll
        for (int s = 0; s < FSPLIT; s++) {
            if (pv[s].x <= a1 + TAU) {
                mask |= 1 << s;
                int qp = atomicAdd(&qcnt[s], 1);
                ql[s * NROWS + qp] = pos;
            }
        }
        widx[n] = ~(pos | (mask << 14));      // marker: resolve in episem
        int l = atomicAdd(&lcnt, 1);
        lrow[l] = n; lpos[l] = pos;
    } else {
        widx[n] = ai;
        out[OFF_IDX + n] = (float)ai;
    }
    __syncthreads();
    const int lc = lcnt;
    for (int it = 0; it < lc; it++) {
        int pos = lpos[it];
        if (pos < CAPROWS) {
            int rn = lrow[it];
            zg[(size_t)pos * D + tid] =
                z[((size_t)((rn >> 11) * CH + tid)) * T + (rn & 2047)];
        }
    }
}

// -------- exact np-pipeline rescue (queued): 32 rows x 512 codes ------------
__global__ __launch_bounds__(256, 2) void k_rescuex(
        const float* __restrict__ z, const float* __restrict__ cb,
        const float* __restrict__ c2, const float* __restrict__ z2,
        const int* __restrict__ list, const int* __restrict__ qcnt,
        const int* __restrict__ ql,
        const float* __restrict__ zg, float2* __restrict__ pr) {
    __shared__ float zs[D][MT + 4];       // 36 KB (pad: aligned f4)
    __shared__ float cs[2][DC][KT + 4];   // 33.8 KB double-buffered
    __shared__ float c2s[512];            // 2 KB
    __shared__ int   ls[MT];
    __shared__ int   lpo[MT];
    __shared__ float z2sh[MT];
    const int tid = threadIdx.x;
    const int tx = tid & 31, ty = tid >> 5;
    const int fs = blockIdx.x & 3, sub = (blockIdx.x >> 2) & 3;
    const int grp = blockIdx.x >> 4;
    const int qc = qcnt[fs];
    const int base = grp * MT;
    if (base >= qc) return;
    const int nr = min(MT, qc - base);
    const int kbase = fs * 2048 + sub * 512;
    const int rs = fs * 4 + sub;
    const int kl = tid & 127, half = tid >> 7;

    if (tid < MT) {
        int qi = base + ((tid < nr) ? tid : (nr - 1));
        int pos = ql[fs * NROWS + qi];
        int n = list[pos];
        ls[tid] = n; lpo[tid] = pos;
        z2sh[tid] = z2[n];
    }
    #pragma unroll
    for (int i = 0; i < 2; i++)
        c2s[tid + i * 256] = c2[kbase + tid + i * 256];

    float4 rv0, rv1, rv2, rv3;
    auto ldchunk = [&](int ch) {
        const int k0 = kbase + (ch >> 3) * KT, dcc = (ch & 7) * DC;
        const float4* src = (const float4*)(cb + (size_t)(k0 + kl) * D + dcc + half * 16);
        rv0 = src[0]; rv1 = src[1]; rv2 = src[2]; rv3 = src[3];
    };
    auto wrchunk = [&](int b) {
        const int dl = half * 16;
        cs[b][dl + 0][kl] = rv0.x; cs[b][dl + 1][kl] = rv0.y;
        cs[b][dl + 2][kl] = rv0.z; cs[b][dl + 3][kl] = rv0.w;
        cs[b][dl + 4][kl] = rv1.x; cs[b][dl + 5][kl] = rv1.y;
        cs[b][dl + 6][kl] = rv1.z; cs[b][dl + 7][kl] = rv1.w;
        cs[b][dl + 8][kl] = rv2.x; cs[b][dl + 9][kl] = rv2.y;
        cs[b][dl + 10][kl] = rv2.z; cs[b][dl + 11][kl] = rv2.w;
        cs[b][dl + 12][kl] = rv3.x; cs[b][dl + 13][kl] = rv3.y;
        cs[b][dl + 14][kl] = rv3.z; cs[b][dl + 15][kl] = rv3.w;
    };

    ldchunk(0);                               // in flight under zs fill
    __syncthreads();                          // ls/lpo visible
    for (int i = tid; i < MT * 64; i += 256) {
        int r = i >> 6, dq = (i & 63) << 2;
        int po = lpo[r];
        if (po < CAPROWS) {
            float4 v = *(const float4*)(zg + (size_t)po * D + dq);
            zs[dq + 0][r] = v.x; zs[dq + 1][r] = v.y;
            zs[dq + 2][r] = v.z; zs[dq + 3][r] = v.w;
        } else {                              // overflow fallback: scattered z
            int n = ls[r];
            #pragma unroll
            for (int e = 0; e < 4; e++)
                zs[dq + e][r] = z[((size_t)((n >> 11) * CH + dq + e)) * T + (n & 2047)];
        }
    }
    __syncthreads();
    wrchunk(0);
    ldchunk(1);
    asm volatile("s_waitcnt lgkmcnt(0)" ::: "memory");
    __builtin_amdgcn_s_barrier();
    __builtin_amdgcn_sched_barrier(0);

    float z2r[4];
    #pragma unroll
    for (int i = 0; i < 4; i++) z2r[i] = z2sh[ty * 4 + i];

    float m1[4]; int bi[4];
    #pragma unroll
    for (int i = 0; i < 4; i++) { m1[i] = FLT_MAX; bi[i] = 0x7fffffff; }
    float acc[4][4] = {};

    const int NCH = (512 / KT) * (D / DC);    // 32 chunks
    for (int ch = 0; ch < NCH; ch++) {
        const int b = ch & 1;
        const int dcc = (ch & 7) * DC;
        #pragma unroll 8
        for (int d = 0; d < DC; d++) {
            const float4 zf = *(const float4*)&zs[dcc + d][ty * 4];
            const float4 cf = *(const float4*)&cs[b][d][tx * 4];
            const float za[4] = {zf.x, zf.y, zf.z, zf.w};
            const float ca[4] = {cf.x, cf.y, cf.z, cf.w};
            #pragma unroll
            for (int i = 0; i < 4; i++)
                #pragma unroll
                for (int j = 0; j < 4; j++)
                    acc[i][j] = fmaf(za[i], ca[j], acc[i][j]);
        }
        if ((ch & 7) == 7) {
            const int koff = (ch >> 3) * KT;
            #pragma unroll
            for (int j = 0; j < 4; j++) {
                int kk = kbase + koff + tx * 4 + j;
                float c2v = c2s[koff + tx * 4 + j];
                #pragma unroll
                for (int i = 0; i < 4; i++) {
                    float tpre = z2r[i] - 2.0f * acc[i][j];   // np combine order
                    float s = tpre + c2v;
                    if (s < m1[i]) { m1[i] = s; bi[i] = kk; } // strict <
                }
            }
            #pragma unroll
            for (int i = 0; i < 4; i++)
                #pragma unroll
                for (int j = 0; j < 4; j++) acc[i][j] = 0.0f;
        }
        if (ch < NCH - 1) {
            __syncthreads();
            wrchunk(b ^ 1);
            if (ch < NCH - 2) ldchunk(ch + 2);
            asm volatile("s_waitcnt lgkmcnt(0)" ::: "memory");
            __builtin_amdgcn_s_barrier();
            __builtin_amdgcn_sched_barrier(0);
        }
    }
    __syncthreads();
    float* rm1 = (float*)zs;
    int*   rix = (int*)(rm1 + MT * 32);
    #pragma unroll
    for (int i = 0; i < 4; i++) {
        int slot = (ty * 4 + i) * 32 + tx;
        rm1[slot] = m1[i]; rix[slot] = bi[i];
    }
    __syncthreads();
    if (tid < MT) {
        float a1 = FLT_MAX; int ai = 0x7fffffff;
        for (int t = 0; t < 32; t++) {
            float b1 = rm1[tid * 32 + t]; int bidx = rix[tid * 32 + t];
            if (b1 < a1 || (b1 == a1 && bidx < ai)) { a1 = b1; ai = bidx; }
        }
        if (tid < nr)
            pr[(size_t)rs * NROWS + lpo[tid]] = make_float2(a1, __int_as_float(ai));
    }
}

// ---------------- fallback exact fp32 GEMM-argmin (Round-3, passing) --------
__global__ __launch_bounds__(256) void k_exact(
        const float* __restrict__ z, const float* __restrict__ cb,
        const float* __restrict__ c2, const float* __restrict__ z2,
        float2* __restrict__ part) {
    __shared__ float zs[D][MT];
    __shared__ float cs[DC][KT + 4];
    const int tid = threadIdx.x;
    const int tx = tid & 31, ty = tid >> 5;
    const int n0 = blockIdx.x * MT;
    const int bb = n0 >> 11, t0 = n0 & 2047;
    const int kbase = blockIdx.y * (K / NSPLIT);
    for (int i = tid; i < D * (MT / 4); i += 256) {
        int d = i >> 3, tg = i & 7;
        float4 v = *(const float4*)(z + ((size_t)(bb * CH + d)) * T + t0 + tg * 4);
        *(float4*)&zs[d][tg * 4] = v;
    }
    float z2r[4];
    #pragma unroll
    for (int i = 0; i < 4; i++) z2r[i] = z2[n0 + ty * 4 + i];
    float m1[4]; int bi[4];
    #pragma unroll
    for (int i = 0; i < 4; i++) { m1[i] = FLT_MAX; bi[i] = 0x7fffffff; }
    for (int ktt = 0; ktt < K / NSPLIT; ktt += KT) {
        const int k0 = kbase + ktt;
        float acc[4][4] = {};
        for (int dc = 0; dc < D; dc += DC) {
            __syncthreads();
            {
                int kl = tid & 127, half = tid >> 7;
                const float4* src = (const float4*)(cb + (size_t)(k0 + kl) * D + dc + half * 16);
                #pragma unroll
                for (int j = 0; j < 4; j++) {
                    float4 v = src[j];
                    int dl = half * 16 + j * 4;
                    cs[dl + 0][kl] = v.x; cs[dl + 1][kl] = v.y;
                    cs[dl + 2][kl] = v.z; cs[dl + 3][kl] = v.w;
                }
            }
            __syncthreads();
            #pragma unroll 8
            for (int d = 0; d < DC; d++) {
                const float4 zf = *(const float4*)&zs[dc + d][ty * 4];
                const float4 cf = *(const float4*)&cs[d][tx * 4];
                const float za[4] = {zf.x, zf.y, zf.z, zf.w};
                const float ca[4] = {cf.x, cf.y, cf.z, cf.w};
                #pragma unroll
                for (int i = 0; i < 4; i++)
                    #pragma unroll
                    for (int j = 0; j < 4; j++)
                        acc[i][j] = fmaf(za[i], ca[j], acc[i][j]);
            }
        }
        #pragma unroll
        for (int j = 0; j < 4; j++) {
            int kk = k0 + tx * 4 + j;
            float c2v = c2[kk];
            #pragma unroll
            for (int i = 0; i < 4; i++) {
                float tpre = z2r[i] - 2.0f * acc[i][j];
                float s = tpre + c2v;
                if (s < m1[i]) { m1[i] = s; bi[i] = kk; }
            }
        }
    }
    __syncthreads();
    float* rm1 = (float*)zs;
    int*   rix = (int*)(rm1 + MT * 32);
    #pragma unroll
    for (int i = 0; i < 4; i++) {
        int slot = (ty * 4 + i) * 32 + tx;
        rm1[slot] = m1[i]; rix[slot] = bi[i];
    }
    __syncthreads();
    if (tid < MT) {
        float a1 = FLT_MAX; int ai = 0x7fffffff;
        for (int t = 0; t < 32; t++) {
            float b1 = rm1[tid * 32 + t]; int bidx = rix[tid * 32 + t];
            if (b1 < a1 || (b1 == a1 && bidx < ai)) { a1 = b1; ai = bidx; }
        }
        part[(size_t)(n0 + tid) * NSPLIT + blockIdx.y] = make_float2(a1, __int_as_float(ai));
    }
}

__global__ void k_reduce(const float2* __restrict__ part, int* __restrict__ widx,
                         float* __restrict__ out) {
    int n = blockIdx.x * 256 + threadIdx.x;
    float a1 = FLT_MAX; int ai = 0x7fffffff;
    #pragma unroll
    for (int s = 0; s < NSPLIT; s++) {
        float2 p = part[(size_t)n * NSPLIT + s];
        float b1 = p.x; int bidx = __float_as_int(p.y);
        if (b1 < a1 || (b1 == a1 && bidx < ai)) { a1 = b1; ai = bidx; }
    }
    widx[n] = ai;
    out[OFF_IDX + n] = (float)ai;
}

// ------- epilogue: gather z_q + loss partials; masked rescue-split merge ----
__global__ __launch_bounds__(256) void k_episem(
        const float* __restrict__ z, const float* __restrict__ cb,
        const int* __restrict__ widx, const float2* __restrict__ pr,
        float* __restrict__ out, double* __restrict__ lossp) {
    __shared__ int qidx[32];
    __shared__ float qs[32][260];
    __shared__ double wsum[4];
    const int tid = threadIdx.x;
    const int bb = blockIdx.x >> 6;
    const int t0 = (blockIdx.x & 63) * 32;
    if (tid < 32) {
        int n = bb * T + t0 + tid;
        int wv = widx[n];
        if (wv < 0) {
            unsigned u = ~wv;
            int pos = u & 16383;
            int mask = (u >> 14) & 15;
            float a1 = FLT_MAX; int ai = 0x7fffffff;
            #pragma unroll
            for (int s = 0; s < RSPLIT; s++) {
                if ((mask >> (s >> 2)) & 1) {
                    float2 p = pr[(size_t)s * NROWS + pos];
                    float v = p.x; int ix = __float_as_int(p.y);
                    if (v < a1 || (v == a1 && ix < ai)) { a1 = v; ai = ix; }
                }
            }
            wv = ai;
            out[OFF_IDX + n] = (float)ai;
        }
        qidx[tid] = wv;
    }
    __syncthreads();
    for (int i = tid; i < 32 * 64; i += 256) {
        int tl = i >> 6, lanee = i & 63;
        float4 v = *(const float4*)(cb + (size_t)qidx[tl] * D + lanee * 4);
        *(float4*)&qs[tl][lanee * 4] = v;
    }
    __syncthreads();
    double ls = 0.0;
    for (int it = 0; it < 32; it++) {
        int d = it * 8 + (tid >> 5);
        int tl = tid & 31;
        size_t ga = ((size_t)(bb * CH + d)) * T + t0 + tl;
        float q = qs[tl][d];
        float e = q - z[ga];
        out[ga] = q;
        ls += (double)e * (double)e;
    }
    #pragma unroll
    for (int off = 32; off; off >>= 1) ls += __shfl_down(ls, off, 64);
    if ((tid & 63) == 0) wsum[tid >> 6] = ls;
    __syncthreads();
    if (tid == 0) lossp[blockIdx.x] = wsum[0] + wsum[1] + wsum[2] + wsum[3];
}

// ------------- loss finalize (1 block) -------------
__global__ void k_loss(const double* __restrict__ lossp, float* __restrict__ out) {
    __shared__ double sm[256];
    int tid = threadIdx.x;
    sm[tid] = lossp[tid] + lossp[tid + 256];
    __syncthreads();
    for (int off = 128; off; off >>= 1) {
        if (tid < off) sm[tid] += sm[tid + off];
        __syncthreads();
    }
    if (tid == 0) out[OFF_LOSS] = (float)(1.1 * sm[0] / (double)(BQ * D * T));
}

// ------------- fallback epilogue variants (fallback path only) -------------
__global__ __launch_bounds__(256) void k_episemf(
        const float* __restrict__ z, const float* __restrict__ cb,
        const int* __restrict__ widx, float* __restrict__ out, double* __restrict__ lossp) {
    __shared__ int qidx[32];
    __shared__ float qs[32][260];
    __shared__ double wsum[4];
    const int tid = threadIdx.x;
    const int bb = blockIdx.x >> 6;
    const int t0 = (blockIdx.x & 63) * 32;
    if (tid < 32) qidx[tid] = widx[bb * T + t0 + tid];
    __syncthreads();
    for (int i = tid; i < 32 * 64; i += 256) {
        int tl = i >> 6, lanee = i & 63;
        float4 v = *(const float4*)(cb + (size_t)qidx[tl] * D + lanee * 4);
        *(float4*)&qs[tl][lanee * 4] = v;
    }
    __syncthreads();
    double ls = 0.0;
    for (int it = 0; it < 32; it++) {
        int d = it * 8 + (tid >> 5);
        int tl = tid & 31;
        size_t ga = ((size_t)(bb * CH + d)) * T + t0 + tl;
        float q = qs[tl][d];
        float e = q - z[ga];
        out[ga] = q;
        ls += (double)e * (double)e;
    }
    #pragma unroll
    for (int off = 32; off; off >>= 1) ls += __shfl_down(ls, off, 64);
    if ((tid & 63) == 0) wsum[tid >> 6] = ls;
    __syncthreads();
    if (tid == 0) lossp[blockIdx.x] = wsum[0] + wsum[1] + wsum[2] + wsum[3];
}

__global__ void k_epiac(const float* __restrict__ z, const double* __restrict__ lossp,
                        float* __restrict__ out) {
    __shared__ double sm[256];
    int i = (blockIdx.x * 256 + threadIdx.x) * 4;   // grid exact: no early return
    int b = i / (DAC * T);
    int r = i % (DAC * T);
    int d = r / T, t = r % T;
    size_t zoff = ((size_t)(b * CH + 256 + d)) * T + t;
    float4 v = *(const float4*)(z + zoff);
    float r0, r1, r2, r3;
    {
        float t0 = (float)tanh((double)v.x); r0 = rintf(t0 * 10.0f);
        float t1 = (float)tanh((double)v.y); r1 = rintf(t1 * 10.0f);
        float t2 = (float)tanh((double)v.z); r2 = rintf(t2 * 10.0f);
        float t3 = (float)tanh((double)v.w); r3 = rintf(t3 * 10.0f);
    }
    *(float4*)(out + zoff) = make_float4(r0, r1, r2, r3);
    size_t co = OFF_CODES + (size_t)(b * DAC + d) * T + t;
    *(float4*)(out + co) = make_float4(r0 + 10.0f, r1 + 10.0f, r2 + 10.0f, r3 + 10.0f);
    size_t ao = OFF_ACQ + (size_t)(b * DAC + d) * T + t;
    out[ao + 0] = r0; out[ao + 1] = r1; out[ao + 2] = r2; out[ao + 3] = r3;
    if (blockIdx.x == 0) {
        int tid = threadIdx.x;
        sm[tid] = lossp[tid] + lossp[tid + 256];
        __syncthreads();
        for (int off = 128; off; off >>= 1) {
            if (tid < off) sm[tid] += sm[tid + off];
            __syncthreads();
        }
        if (tid == 0) out[OFF_LOSS] = (float)(1.1 * sm[0] / (double)(BQ * D * T));
    }
}

extern "C" void kernel_launch(void* const* d_in, const int* in_sizes, int n_in,
                              void* d_out, int out_size, void* d_ws, size_t ws_size,
                              hipStream_t stream) {
    const float* z  = (const float*)d_in[0];
    const float* cb = (const float*)d_in[1];
    float* out = (float*)d_out;
    char* ws = (char*)d_ws;

    if (ws_size >= (size_t)WN_NEED) {
        float*  c2    = (float*)(ws + WN_C2);
        float*  z2    = (float*)(ws + WN_Z2);
        int*    cnt   = (int*)(ws + WN_CNT);
        int*    list  = (int*)(ws + WN_LIST);
        double* lossp = (double*)(ws + WN_LOSS);
        int*    widx  = (int*)(ws + WN_WIDX);
        int*    qcnt  = (int*)(ws + WN_QCNT);
        int*    ql    = (int*)(ws + WN_QL);
        float4* pmx   = (float4*)(ws + WN_PMX);
        unsigned short* Az = (unsigned short*)(ws + WN_AZ);
        unsigned short* Bc = (unsigned short*)(ws + WN_BC);
        float*  zg    = (float*)(ws + WN_ZG);    // aliases Az (dead after k_fast)
        float2* pr    = (float2*)(ws + WN_PR);   // aliases pmx (dead after k_reduce2)

        hipLaunchKernelGGL(k_prep,    dim3(K / 4 + 512 + BQ * DAC * T / 1024), dim3(256), 0, stream,
                           z, cb, Az, Bc, c2, z2, cnt, qcnt, out);
        hipLaunchKernelGGL(k_fast,    dim3(128 * FSPLIT), dim3(256), 0, stream, Az, Bc, c2, pmx);
        hipLaunchKernelGGL(k_reduce2, dim3(NROWS / 256),  dim3(256), 0, stream,
                           pmx, widx, cnt, list, out, z, zg, qcnt, ql);
        hipLaunchKernelGGL(k_rescuex, dim3((NROWS / MT) * RSPLIT), dim3(256), 0, stream,
                           z, cb, c2, z2, list, qcnt, ql, zg, pr);
        hipLaunchKernelGGL(k_episem,  dim3(BQ * (T / 32)), dim3(256), 0, stream,
                           z, cb, widx, pr, out, lossp);
        hipLaunchKernelGGL(k_loss,    dim3(1),            dim3(256), 0, stream, lossp, out);
    } else {
        float*  c2    = (float*)(ws + WS_C2);
        float*  z2    = (float*)(ws + WS_Z2);
        float2* part  = (float2*)(ws + WS_PART);
        int*    widx  = (int*)(ws + WS_IDX);
        double* lossp = (double*)(ws + WS_LOSS);
        hipLaunchKernelGGL(k_c2pw,   dim3(K / 256),            dim3(256), 0, stream, cb, c2);
        hipLaunchKernelGGL(k_z2pw,   dim3(NROWS / 256),        dim3(256), 0, stream, z, z2);
        hipLaunchKernelGGL(k_exact,  dim3(NROWS / MT, NSPLIT), dim3(256), 0, stream, z, cb, c2, z2, part);
        hipLaunchKernelGGL(k_reduce, dim3(NROWS / 256),        dim3(256), 0, stream, part, widx, out);
        hipLaunchKernelGGL(k_episemf, dim3(BQ * (T / 32)),     dim3(256), 0, stream, z, cb, widx, out, lossp);
        hipLaunchKernelGGL(k_epiac,  dim3(BQ * DAC * T / 1024), dim3(256), 0, stream, z, lossp, out);
    }
}